// Round 1
// baseline (421.166 us; speedup 1.0000x reference)
//
#include <hip/hip_runtime.h>

// RelationLayer, round 13.
// R12 = 259.3us; pair_kernel 114us with MfmaUtil 13.6 / VALUBusy 29.7 /
// Occupancy 22% -> latency-bound, residency-capped: 68KB LDS (2 blocks/CU)
// AND 96 VGPR (5 waves/SIMD, 3 blocks need 6) both cap at 2 blocks/CU.
// R13: pair re-tiled to ONE b per block: grid (64,32), 64 j-rows x K=128,
// LDS 34.8KB, acc regs halved (hi/cr [2][2]), __launch_bounds__(512,6)
// -> 3 resident blocks = 24 waves/CU. Total staged work unchanged (rows
// were (j,b) pairs); epilogue gains a cross-wm combine (both m-halves are
// j-halves of the same (i,b) row). conv/ab unchanged this round.

#define BB 32
#define CCH 384

__device__ __forceinline__ float leaky(float x) { return fmaxf(x, 0.1f * x); }

typedef _Float16 f16x8 __attribute__((ext_vector_type(8)));
typedef float f32x4 __attribute__((ext_vector_type(4)));

union F8 { uint4 q; f16x8 h; };
union H2 { _Float16 f[2]; uint32_t u; };

__device__ __forceinline__ void split2(float d0, float d1,
                                       uint32_t& hw, uint32_t& lw) {
  H2 h, l;
  h.f[0] = (_Float16)d0; h.f[1] = (_Float16)d1;
  l.f[0] = (_Float16)((d0 - (float)h.f[0]) * 2048.0f);
  l.f[1] = (_Float16)((d1 - (float)h.f[1]) * 2048.0f);
  hw = h.u; lw = l.u;
}

// ---------------------------------------------------------------- conv ------
// grid 192 = 32 m-tiles(64 rows) x 6 n-tiles(64 ch): nb 0..3 win1 (K=512),
// nb 4..5 win3 (K=1536, taps in-K). Output yG[c][row] recombined, c<384.
__global__ __launch_bounds__(256) void conv_kernel(
    const float* __restrict__ x, const float* __restrict__ mask,
    const float* __restrict__ cw0, const float* __restrict__ cw1,
    float* __restrict__ yG, float* __restrict__ Ssum, float* __restrict__ Ssq)
{
  __shared__ uint32_t Ah[64 * 68], Al[64 * 68];
  __shared__ uint32_t Bh[64 * 68], Bl[64 * 68];
  int bx = blockIdx.x;
  int nb = bx % 6, mb = bx / 6;
  int n0 = nb * 64;
  int row0 = mb * 64;
  bool w3 = (nb >= 4);
  int nch = w3 ? 12 : 4;
  const float* wbase = w3 ? (cw1 + (n0 - 256) * 1536) : (cw0 + n0 * 512);
  int wK = w3 ? 1536 : 512;

  int tid = threadIdx.x;
  int wid = __builtin_amdgcn_readfirstlane(tid >> 6);
  int wm = wid & 1, wn2 = wid >> 1;
  int lane = tid & 63;
  int m16 = lane & 15, q = lane >> 4;

  f32x4 hi[2][2], cr[2][2];
#pragma unroll
  for (int a = 0; a < 2; ++a)
#pragma unroll
    for (int b = 0; b < 2; ++b) {
      hi[a][b] = (f32x4){0.f, 0.f, 0.f, 0.f};
      cr[a][b] = (f32x4){0.f, 0.f, 0.f, 0.f};
    }

#pragma unroll 1
  for (int ch = 0; ch < nch; ++ch) {
    int kg0 = ch * 128;
    int tap = kg0 >> 9;
    int d0 = kg0 & 511;
    int shift = w3 ? (tap - 1) * 32 : 0;
    __syncthreads();                     // prior chunk's frag reads done
#pragma unroll 1
    for (int it = 0; it < 4; ++it) {
      int idx = it * 256 + tid;
      int r = idx >> 4;                  // 0..63
      int k8 = (idx & 15) * 8;           // 0..120
      // A: x * mask, row-shifted per tap, zero-padded at edges
      float d[8];
      int rowg = row0 + r + shift;
      if ((unsigned)rowg < 2048u) {
        float mv = mask[rowg];
        const float* xp = x + rowg * 512 + d0 + k8;
        float4 a0 = *(const float4*)xp;
        float4 a1 = *(const float4*)(xp + 4);
        d[0] = a0.x * mv; d[1] = a0.y * mv; d[2] = a0.z * mv; d[3] = a0.w * mv;
        d[4] = a1.x * mv; d[5] = a1.y * mv; d[6] = a1.z * mv; d[7] = a1.w * mv;
      } else {
#pragma unroll
        for (int t2 = 0; t2 < 8; ++t2) d[t2] = 0.f;
      }
      uint4 hq, lq;
      split2(d[0], d[1], hq.x, lq.x);
      split2(d[2], d[3], hq.y, lq.y);
      split2(d[4], d[5], hq.z, lq.z);
      split2(d[6], d[7], hq.w, lq.w);
      *(uint4*)&Ah[r * 68 + k8 / 2] = hq;
      *(uint4*)&Al[r * 68 + k8 / 2] = lq;
      // B: conv weights (cw1 k-layout is already tap-major -> direct)
      const float* wp = wbase + r * wK + kg0 + k8;
      float4 b0v = *(const float4*)wp;
      float4 b1v = *(const float4*)(wp + 4);
      split2(b0v.x, b0v.y, hq.x, lq.x);
      split2(b0v.z, b0v.w, hq.y, lq.y);
      split2(b1v.x, b1v.y, hq.z, lq.z);
      split2(b1v.z, b1v.w, hq.w, lq.w);
      *(uint4*)&Bh[r * 68 + k8 / 2] = hq;
      *(uint4*)&Bl[r * 68 + k8 / 2] = lq;
    }
    __syncthreads();
#pragma unroll
    for (int ks = 0; ks < 4; ++ks) {
      int koff = ks * 16 + q * 4;
      F8 bh[2], bl[2];
#pragma unroll
      for (int nt = 0; nt < 2; ++nt) {
        int br = wn2 * 32 + nt * 16 + m16;
        bh[nt].q = *(const uint4*)&Bh[br * 68 + koff];
        bl[nt].q = *(const uint4*)&Bl[br * 68 + koff];
      }
#pragma unroll
      for (int mt = 0; mt < 2; ++mt) {
        int ar = wm * 32 + mt * 16 + m16;
        F8 ah, al;
        ah.q = *(const uint4*)&Ah[ar * 68 + koff];
        al.q = *(const uint4*)&Al[ar * 68 + koff];
#pragma unroll
        for (int nt = 0; nt < 2; ++nt) {
          hi[mt][nt] = __builtin_amdgcn_mfma_f32_16x16x32_f16(
              ah.h, bh[nt].h, hi[mt][nt], 0, 0, 0);
          cr[mt][nt] = __builtin_amdgcn_mfma_f32_16x16x32_f16(
              ah.h, bl[nt].h, cr[mt][nt], 0, 0, 0);
          cr[mt][nt] = __builtin_amdgcn_mfma_f32_16x16x32_f16(
              al.h, bh[nt].h, cr[mt][nt], 0, 0, 0);
        }
      }
    }
  }

  // combine products
  float y[2][2][4];
#pragma unroll
  for (int mt = 0; mt < 2; ++mt)
#pragma unroll
    for (int nt = 0; nt < 2; ++nt)
#pragma unroll
      for (int rg = 0; rg < 4; ++rg)
        y[mt][nt][rg] = hi[mt][nt][rg] + cr[mt][nt][rg] * (1.0f / 2048.0f);

  // fused BN stats: per-channel sum / sumsq over this block's 64 rows
#pragma unroll
  for (int nt = 0; nt < 2; ++nt) {
    float s = 0.f, s2 = 0.f;
#pragma unroll
    for (int mt = 0; mt < 2; ++mt)
#pragma unroll
      for (int rg = 0; rg < 4; ++rg) {
        float v = y[mt][nt][rg];
        s += v; s2 += v * v;
      }
    s  += __shfl_xor(s, 16, 64);  s  += __shfl_xor(s, 32, 64);
    s2 += __shfl_xor(s2, 16, 64); s2 += __shfl_xor(s2, 32, 64);
    if (lane < 16) {
      int c = n0 + wn2 * 32 + nt * 16 + m16;
      atomicAdd(&Ssum[c], s);
      atomicAdd(&Ssq[c], s2);
    }
  }

  // store yG[c][row] via LDS transpose (coalesced 64B runs)
  __syncthreads();
  float* Yl = (float*)Ah;                // 64 x 68 floats (fits in Ah)
#pragma unroll
  for (int mt = 0; mt < 2; ++mt)
#pragma unroll
    for (int nt = 0; nt < 2; ++nt)
#pragma unroll
      for (int rg = 0; rg < 4; ++rg)
        Yl[(wn2 * 32 + nt * 16 + m16) * 68 + wm * 32 + mt * 16 + q * 4 + rg] =
            y[mt][nt][rg];
  __syncthreads();
  {
    int c = tid >> 2, seg = (tid & 3) * 16;
#pragma unroll
    for (int j = 0; j < 16; j += 4)
      *(float4*)&yG[(n0 + c) * 2048 + row0 + seg + j] =
          *(const float4*)&Yl[c * 68 + seg + j];
  }
}

// ------------------------------------------------------------------ ab ------
// grid 352: blocks 0..255 = ab GEMM (scale/shift computed inline from atomic
// sums); 256..351 = wsplit for w1..w3.
__global__ __launch_bounds__(256) void ab_kernel(
    const float* __restrict__ yG, const float* __restrict__ Ssum,
    const float* __restrict__ Ssq,
    const float* __restrict__ g0, const float* __restrict__ be0,
    const float* __restrict__ g1, const float* __restrict__ be1,
    const float* __restrict__ mask, const float* __restrict__ w0,
    const float* __restrict__ w1, const float* __restrict__ w2,
    const float* __restrict__ w3, uint32_t* __restrict__ wpk,
    float* __restrict__ a_arr, float* __restrict__ bb_arr)
{
  int bx = blockIdx.x;
  int tid = threadIdx.x;
  if (bx >= 256) {
    int e = (bx - 256) * 256 + tid;       // 0..24575 (L, k2, n)
    int L = e >> 13;
    int r = e & 8191;
    int k2 = r >> 7, n = r & 127;
    int k = k2 * 2;
    const float* w = (L == 0) ? w1 : (L == 1) ? w2 : w3;
    uint32_t hw, lw;
    split2(w[k * 128 + n], w[(k + 1) * 128 + n], hw, lw);
    wpk[L * 8192 + n * 64 + k2] = hw;
    wpk[24576 + L * 8192 + n * 64 + k2] = lw;
    return;
  }
  __shared__ float As[32 * 36];
  __shared__ float Ws[32 * 68];
  __shared__ float scs[384], shs[384];
  // scale/shift from fused-atomics stats (BN + gamma/beta fold)
  for (int c = tid; c < 384; c += 256) {
    float Sv = Ssum[c], S2v = Ssq[c];
    float mean = Sv * (1.f / 2048.f);
    float var  = S2v * (1.f / 2048.f) - mean * mean;
    float g  = (c < 256) ? g0[c] : g1[c - 256];
    float be = (c < 256) ? be0[c] : be1[c - 256];
    float sc = g / sqrtf(var + 1e-5f);
    scs[c] = sc;
    shs[c] = be - mean * sc;
  }
  __syncthreads();

  int rt = bx & 63, ct = bx >> 6;
  int row0 = rt * 32, n0 = ct * 64;
  int r4 = (tid >> 5) * 4;
  int n2 = (tid & 31) * 2;
  int scc = tid >> 3, srr4 = (tid & 7) * 4;
  int wnn8 = (tid & 7) * 8;
  const float* wbase = (n0 < 128) ? (w0 + n0) : (w0 + CCH * 128 + (n0 - 128));
  float4 mv = *(const float4*)(mask + row0 + srr4);

  float acc[4][2] = {{0.f, 0.f}};
#pragma unroll 1
  for (int c0 = 0; c0 < 384; c0 += 32) {
    int c = c0 + scc;
    float4 yv = *(const float4*)(yG + c * 2048 + row0 + srr4);
    float sc = scs[c], sh = shs[c];
    float4 wv0 = *(const float4*)(wbase + c * 128 + wnn8);
    float4 wv1 = *(const float4*)(wbase + c * 128 + wnn8 + 4);
    __syncthreads();
    float4 hv;
    hv.x = leaky(fmaf(yv.x, sc, sh)) * mv.x;
    hv.y = leaky(fmaf(yv.y, sc, sh)) * mv.y;
    hv.z = leaky(fmaf(yv.z, sc, sh)) * mv.z;
    hv.w = leaky(fmaf(yv.w, sc, sh)) * mv.w;
    *(float4*)&As[scc * 36 + srr4] = hv;
    *(float4*)&Ws[scc * 68 + wnn8] = wv0;
    *(float4*)&Ws[scc * 68 + wnn8 + 4] = wv1;
    __syncthreads();
#pragma unroll
    for (int cc = 0; cc < 32; ++cc) {
      float4 a = *(const float4*)&As[cc * 36 + r4];
      float2 w = *(const float2*)&Ws[cc * 68 + n2];
      acc[0][0] = fmaf(a.x, w.x, acc[0][0]); acc[0][1] = fmaf(a.x, w.y, acc[0][1]);
      acc[1][0] = fmaf(a.y, w.x, acc[1][0]); acc[1][1] = fmaf(a.y, w.y, acc[1][1]);
      acc[2][0] = fmaf(a.z, w.x, acc[2][0]); acc[2][1] = fmaf(a.z, w.y, acc[2][1]);
      acc[3][0] = fmaf(a.w, w.x, acc[3][0]); acc[3][1] = fmaf(a.w, w.y, acc[3][1]);
    }
  }
  float* dst; int nd;
  if (n0 < 128) { dst = a_arr; nd = n0; } else { dst = bb_arr; nd = n0 - 128; }
#pragma unroll
  for (int ri = 0; ri < 4; ++ri)
    *(float2*)&dst[(row0 + r4 + ri) * 128 + nd + n2] = make_float2(acc[ri][0], acc[ri][1]);
}

// ---------------------------------------------------------------- pair ------
// R13: grid (64,32) = one (i,b) per block, 64 j-rows, K=128.
// 512 thr = 8 waves (2m x 4n), LDS 34.8KB, launch_bounds(512,6) -> 3 blk/CU.
__global__ __launch_bounds__(512, 6) void pair_kernel(
    const float* __restrict__ a_arr, const float* __restrict__ bb_arr,
    const float* __restrict__ b0, const uint32_t* __restrict__ wpk,
    const float* __restrict__ b1, const float* __restrict__ b2,
    const float* __restrict__ b3,
    const float* __restrict__ w4, const float* __restrict__ b4,
    const float* __restrict__ w5, const float* __restrict__ b5,
    const float* __restrict__ mask, float* __restrict__ out)
{
  __shared__ uint32_t Ahs[64 * 68];
  __shared__ uint32_t Als[64 * 68];
  int i = blockIdx.x, b = blockIdx.y;
  int tid = threadIdx.x;
  int browp = i * BB + b;                 // output row (i,b) in (L*B)

  // ---- stage A = leaky(a_i + bb_j + b0), split to f16 hi/lo planes
  {
    int k8 = (tid & 15) * 8;              // same for both its (512 % 16 == 0)
    const float* ap = a_arr + browp * 128 + k8;
    const float* zp = b0 + k8;
    float az[8];
#pragma unroll
    for (int t = 0; t < 8; t += 4) {
      float4 av = *(const float4*)(ap + t);
      float4 zv = *(const float4*)(zp + t);
      az[t + 0] = av.x + zv.x; az[t + 1] = av.y + zv.y;
      az[t + 2] = av.z + zv.z; az[t + 3] = av.w + zv.w;
    }
#pragma unroll
    for (int it = 0; it < 2; ++it) {
      int r = (it * 512 + tid) >> 4;      // j row 0..63
      const float* bbp = bb_arr + (r * BB + b) * 128 + k8;
      float d[8];
#pragma unroll
      for (int t = 0; t < 8; t += 4) {
        float4 bv = *(const float4*)(bbp + t);
        d[t + 0] = leaky(az[t + 0] + bv.x);
        d[t + 1] = leaky(az[t + 1] + bv.y);
        d[t + 2] = leaky(az[t + 2] + bv.z);
        d[t + 3] = leaky(az[t + 3] + bv.w);
      }
      uint4 hq, lq;
      split2(d[0], d[1], hq.x, lq.x);
      split2(d[2], d[3], hq.y, lq.y);
      split2(d[4], d[5], hq.z, lq.z);
      split2(d[6], d[7], hq.w, lq.w);
      *(uint4*)&Ahs[r * 68 + k8 / 2] = hq;
      *(uint4*)&Als[r * 68 + k8 / 2] = lq;
    }
  }
  __syncthreads();

  int wid = __builtin_amdgcn_readfirstlane(tid >> 6);
  int wm = wid & 1, wn = wid >> 1;
  int lane = tid & 63;
  int m16 = lane & 15, q = lane >> 4;

  f32x4 hi[2][2], cr[2][2];

#pragma unroll 1
  for (int L = 0; L < 3; ++L) {
    const uint32_t* WhL = wpk + L * 8192;
    const uint32_t* WlL = wpk + 24576 + L * 8192;
    const float* Bv = (L == 0) ? b1 : (L == 1) ? b2 : b3;
#pragma unroll
    for (int mt = 0; mt < 2; ++mt)
#pragma unroll
      for (int nt = 0; nt < 2; ++nt) {
        hi[mt][nt] = (f32x4){0.f, 0.f, 0.f, 0.f};
        cr[mt][nt] = (f32x4){0.f, 0.f, 0.f, 0.f};
      }

    F8 Wh[2], Wl[2], Whn[2], Wln[2];
#pragma unroll
    for (int nt = 0; nt < 2; ++nt) {
      int wrow = wn * 32 + nt * 16 + m16;
      Wh[nt].q = *(const uint4*)(WhL + wrow * 64 + q * 4);
      Wl[nt].q = *(const uint4*)(WlL + wrow * 64 + q * 4);
    }

#pragma unroll
    for (int ks = 0; ks < 4; ++ks) {
      int koff2 = ks * 16 + q * 4;
      if (ks < 3) {
#pragma unroll
        for (int nt = 0; nt < 2; ++nt) {
          int wrow = wn * 32 + nt * 16 + m16;
          Whn[nt].q = *(const uint4*)(WhL + wrow * 64 + koff2 + 16);
          Wln[nt].q = *(const uint4*)(WlL + wrow * 64 + koff2 + 16);
        }
      }
#pragma unroll
      for (int mt = 0; mt < 2; ++mt) {
        int arow = wm * 32 + mt * 16 + m16;
        F8 Ah, Al;
        Ah.q = *(const uint4*)&Ahs[arow * 68 + koff2];
        Al.q = *(const uint4*)&Als[arow * 68 + koff2];
#pragma unroll
        for (int nt = 0; nt < 2; ++nt) {
          hi[mt][nt] = __builtin_amdgcn_mfma_f32_16x16x32_f16(
              Ah.h, Wh[nt].h, hi[mt][nt], 0, 0, 0);
          cr[mt][nt] = __builtin_amdgcn_mfma_f32_16x16x32_f16(
              Ah.h, Wl[nt].h, cr[mt][nt], 0, 0, 0);
          cr[mt][nt] = __builtin_amdgcn_mfma_f32_16x16x32_f16(
              Al.h, Wh[nt].h, cr[mt][nt], 0, 0, 0);
        }
      }
#pragma unroll
      for (int nt = 0; nt < 2; ++nt) { Wh[nt] = Whn[nt]; Wl[nt] = Wln[nt]; }
    }

    float bias[2];
#pragma unroll
    for (int nt = 0; nt < 2; ++nt) bias[nt] = Bv[wn * 32 + nt * 16 + m16];

    if (L < 2) {
      __syncthreads();
      int par = lane & 1;
#pragma unroll
      for (int mt = 0; mt < 2; ++mt)
#pragma unroll
        for (int nt = 0; nt < 2; ++nt) {
          int colw = (wn * 32 + nt * 16 + (m16 & ~1)) >> 1;
#pragma unroll
          for (int rg = 0; rg < 4; ++rg) {
            float d = leaky(hi[mt][nt][rg] + cr[mt][nt][rg] * (1.0f / 2048.0f)
                            + bias[nt]);
            float dn = __shfl_xor(d, 1, 64);
            float de = par ? dn : d;
            float do_ = par ? d : dn;
            uint32_t hw, lw;
            split2(de, do_, hw, lw);
            int row = wm * 32 + mt * 16 + q * 4 + rg;
            if (par) Als[row * 68 + colw] = lw;
            else     Ahs[row * 68 + colw] = hw;
          }
        }
      __syncthreads();
    } else {
      // mean over j (this block holds all 64 j for its (i,b))
      float s[2] = {0.f, 0.f};
#pragma unroll
      for (int nt = 0; nt < 2; ++nt)
#pragma unroll
        for (int mt = 0; mt < 2; ++mt)
#pragma unroll
          for (int rg = 0; rg < 4; ++rg)
            s[nt] += leaky(hi[mt][nt][rg] + cr[mt][nt][rg] * (1.0f / 2048.0f)
                           + bias[nt]);
      float mfac = (1.0f / 64.0f) * mask[browp];
#pragma unroll
      for (int nt = 0; nt < 2; ++nt) {
        s[nt] += __shfl_xor(s[nt], 16, 64);
        s[nt] += __shfl_xor(s[nt], 32, 64);
      }
      __syncthreads();
      float* scratch = (float*)Ahs;
      float* Pm = scratch;            // 2 wm-halves x 128
      float* Pc = scratch + 256;      // combined p (128)
      float* Tp = scratch + 384;      // 4 partial chunks x 128
      float* T4 = scratch + 896;      // leaky(p@w4+b4) (128)
      if (lane < 16) {
#pragma unroll
        for (int nt = 0; nt < 2; ++nt)
          Pm[wm * 128 + wn * 32 + nt * 16 + m16] = s[nt] * mfac;
      }
      __syncthreads();
      if (tid < 128) Pc[tid] = Pm[tid] + Pm[128 + tid];
      __syncthreads();
      {
        int k = tid & 127, chh = tid >> 7;     // 4 chunks of 32 c
        const float* w4c = w4 + (chh * 32) * 128 + k;
        const float* pc = Pc + chh * 32;
        float t = 0.f;
#pragma unroll 8
        for (int c0 = 0; c0 < 32; c0 += 4) {
          float4 pv = *(const float4*)&pc[c0];
          t = fmaf(pv.x, w4c[(c0 + 0) * 128], t);
          t = fmaf(pv.y, w4c[(c0 + 1) * 128], t);
          t = fmaf(pv.z, w4c[(c0 + 2) * 128], t);
          t = fmaf(pv.w, w4c[(c0 + 3) * 128], t);
        }
        Tp[chh * 128 + k] = t;
      }
      __syncthreads();
      if (tid < 128)
        T4[tid] = leaky(Tp[tid] + Tp[128 + tid] + Tp[256 + tid] +
                        Tp[384 + tid] + b4[tid]);
      __syncthreads();
      {
        float o = b5[tid];
#pragma unroll 4
        for (int c0 = 0; c0 < 128; c0 += 4) {
          float4 tv = *(const float4*)&T4[c0];
          o = fmaf(tv.x, w5[(c0 + 0) * 512 + tid], o);
          o = fmaf(tv.y, w5[(c0 + 1) * 512 + tid], o);
          o = fmaf(tv.z, w5[(c0 + 2) * 512 + tid], o);
          o = fmaf(tv.w, w5[(c0 + 3) * 512 + tid], o);
        }
        out[browp * 512 + tid] = leaky(o) * mask[browp];
      }
    }
  }
}

// -------------------------------------------------------------- launch ------
extern "C" void kernel_launch(void* const* d_in, const int* in_sizes, int n_in,
                              void* d_out, int out_size, void* d_ws, size_t ws_size,
                              hipStream_t stream) {
  const float* x    = (const float*)d_in[0];
  const float* mask = (const float*)d_in[1];
  const float* cw0  = (const float*)d_in[2];
  // d_in[3] conv_b0: cancels in BN
  const float* g0   = (const float*)d_in[4];
  const float* be0  = (const float*)d_in[5];
  const float* cw1  = (const float*)d_in[6];
  // d_in[7] conv_b1: cancels in BN
  const float* g1   = (const float*)d_in[8];
  const float* be1  = (const float*)d_in[9];
  const float* w0   = (const float*)d_in[10];
  const float* b0   = (const float*)d_in[11];
  const float* w1   = (const float*)d_in[12];
  const float* b1   = (const float*)d_in[13];
  const float* w2   = (const float*)d_in[14];
  const float* b2   = (const float*)d_in[15];
  const float* w3   = (const float*)d_in[16];
  const float* b3   = (const float*)d_in[17];
  const float* w4   = (const float*)d_in[18];
  const float* b4   = (const float*)d_in[19];
  const float* w5   = (const float*)d_in[20];
  const float* b5   = (const float*)d_in[21];

  float* ws     = (float*)d_ws;
  float* Ssum   = ws;                         // 384
  float* Ssq    = ws + 384;                   // 384
  float* yG     = ws + 768;                   // 384*2048 = 786432
  uint32_t* wpk = (uint32_t*)(ws + 787200);   // 49152
  float* a_arr  = ws + 836352;                // 2048*128
  float* bb_arr = ws + 1098496;               // 2048*128
  float* outp   = (float*)d_out;

  hipMemsetAsync(Ssum, 0, 768 * sizeof(float), stream);
  conv_kernel<<<192, 256, 0, stream>>>(x, mask, cw0, cw1, yG, Ssum, Ssq);
  ab_kernel<<<352, 256, 0, stream>>>(yG, Ssum, Ssq, g0, be0, g1, be1,
                                     mask, w0, w1, w2, w3, wpk, a_arr, bb_arr);
  dim3 g5(64, 32);
  pair_kernel<<<g5, 512, 0, stream>>>(a_arr, bb_arr, b0, wpk, b1, b2, b3,
                                      w4, b4, w5, b5, mask, outp);
}

// Round 2
// 391.981 us; speedup vs baseline: 1.0745x; 1.0745x over previous
//
#include <hip/hip_runtime.h>

// RelationLayer, round 14.
// R13 (one-b tile + launch_bounds(512,6)) = 421us FAIL: bound forced VGPR
// 96->40 -> massive scratch spill (FETCH 6.8->163MB, WRITE 4->287MB,
// MfmaUtil 5.7%). Tile geometry was fine (passed, absmax 2.4e-7).
// R14: keep the (64,32) one-b tile but restructure waves 2m x 4n -> 1m x 8n:
// each wave owns 16 N-cols x all 64 M-rows. Register demand drops
// structurally: acc hi[4]+cr[4]=32, ONE Wh/Wl frag pair (no double-buffer)
// = 8 -> natural ~65 VGPR, so (512,6)=3 blk/CU is satisfiable WITHOUT spill.
// Epilogue simplifies: per-wave column slice complete after q-fold, no
// cross-wm combine. Cost: A-frag LDS reads x2 (8 waves/row vs 4) ~ +12us
// grid-wide at 69 TB/s. conv/ab unchanged.

#define BB 32
#define CCH 384

__device__ __forceinline__ float leaky(float x) { return fmaxf(x, 0.1f * x); }

typedef _Float16 f16x8 __attribute__((ext_vector_type(8)));
typedef float f32x4 __attribute__((ext_vector_type(4)));

union F8 { uint4 q; f16x8 h; };
union H2 { _Float16 f[2]; uint32_t u; };

__device__ __forceinline__ void split2(float d0, float d1,
                                       uint32_t& hw, uint32_t& lw) {
  H2 h, l;
  h.f[0] = (_Float16)d0; h.f[1] = (_Float16)d1;
  l.f[0] = (_Float16)((d0 - (float)h.f[0]) * 2048.0f);
  l.f[1] = (_Float16)((d1 - (float)h.f[1]) * 2048.0f);
  hw = h.u; lw = l.u;
}

// ---------------------------------------------------------------- conv ------
// grid 192 = 32 m-tiles(64 rows) x 6 n-tiles(64 ch): nb 0..3 win1 (K=512),
// nb 4..5 win3 (K=1536, taps in-K). Output yG[c][row] recombined, c<384.
__global__ __launch_bounds__(256) void conv_kernel(
    const float* __restrict__ x, const float* __restrict__ mask,
    const float* __restrict__ cw0, const float* __restrict__ cw1,
    float* __restrict__ yG, float* __restrict__ Ssum, float* __restrict__ Ssq)
{
  __shared__ uint32_t Ah[64 * 68], Al[64 * 68];
  __shared__ uint32_t Bh[64 * 68], Bl[64 * 68];
  int bx = blockIdx.x;
  int nb = bx % 6, mb = bx / 6;
  int n0 = nb * 64;
  int row0 = mb * 64;
  bool w3 = (nb >= 4);
  int nch = w3 ? 12 : 4;
  const float* wbase = w3 ? (cw1 + (n0 - 256) * 1536) : (cw0 + n0 * 512);
  int wK = w3 ? 1536 : 512;

  int tid = threadIdx.x;
  int wid = __builtin_amdgcn_readfirstlane(tid >> 6);
  int wm = wid & 1, wn2 = wid >> 1;
  int lane = tid & 63;
  int m16 = lane & 15, q = lane >> 4;

  f32x4 hi[2][2], cr[2][2];
#pragma unroll
  for (int a = 0; a < 2; ++a)
#pragma unroll
    for (int b = 0; b < 2; ++b) {
      hi[a][b] = (f32x4){0.f, 0.f, 0.f, 0.f};
      cr[a][b] = (f32x4){0.f, 0.f, 0.f, 0.f};
    }

#pragma unroll 1
  for (int ch = 0; ch < nch; ++ch) {
    int kg0 = ch * 128;
    int tap = kg0 >> 9;
    int d0 = kg0 & 511;
    int shift = w3 ? (tap - 1) * 32 : 0;
    __syncthreads();                     // prior chunk's frag reads done
#pragma unroll 1
    for (int it = 0; it < 4; ++it) {
      int idx = it * 256 + tid;
      int r = idx >> 4;                  // 0..63
      int k8 = (idx & 15) * 8;           // 0..120
      // A: x * mask, row-shifted per tap, zero-padded at edges
      float d[8];
      int rowg = row0 + r + shift;
      if ((unsigned)rowg < 2048u) {
        float mv = mask[rowg];
        const float* xp = x + rowg * 512 + d0 + k8;
        float4 a0 = *(const float4*)xp;
        float4 a1 = *(const float4*)(xp + 4);
        d[0] = a0.x * mv; d[1] = a0.y * mv; d[2] = a0.z * mv; d[3] = a0.w * mv;
        d[4] = a1.x * mv; d[5] = a1.y * mv; d[6] = a1.z * mv; d[7] = a1.w * mv;
      } else {
#pragma unroll
        for (int t2 = 0; t2 < 8; ++t2) d[t2] = 0.f;
      }
      uint4 hq, lq;
      split2(d[0], d[1], hq.x, lq.x);
      split2(d[2], d[3], hq.y, lq.y);
      split2(d[4], d[5], hq.z, lq.z);
      split2(d[6], d[7], hq.w, lq.w);
      *(uint4*)&Ah[r * 68 + k8 / 2] = hq;
      *(uint4*)&Al[r * 68 + k8 / 2] = lq;
      // B: conv weights (cw1 k-layout is already tap-major -> direct)
      const float* wp = wbase + r * wK + kg0 + k8;
      float4 b0v = *(const float4*)wp;
      float4 b1v = *(const float4*)(wp + 4);
      split2(b0v.x, b0v.y, hq.x, lq.x);
      split2(b0v.z, b0v.w, hq.y, lq.y);
      split2(b1v.x, b1v.y, hq.z, lq.z);
      split2(b1v.z, b1v.w, hq.w, lq.w);
      *(uint4*)&Bh[r * 68 + k8 / 2] = hq;
      *(uint4*)&Bl[r * 68 + k8 / 2] = lq;
    }
    __syncthreads();
#pragma unroll
    for (int ks = 0; ks < 4; ++ks) {
      int koff = ks * 16 + q * 4;
      F8 bh[2], bl[2];
#pragma unroll
      for (int nt = 0; nt < 2; ++nt) {
        int br = wn2 * 32 + nt * 16 + m16;
        bh[nt].q = *(const uint4*)&Bh[br * 68 + koff];
        bl[nt].q = *(const uint4*)&Bl[br * 68 + koff];
      }
#pragma unroll
      for (int mt = 0; mt < 2; ++mt) {
        int ar = wm * 32 + mt * 16 + m16;
        F8 ah, al;
        ah.q = *(const uint4*)&Ah[ar * 68 + koff];
        al.q = *(const uint4*)&Al[ar * 68 + koff];
#pragma unroll
        for (int nt = 0; nt < 2; ++nt) {
          hi[mt][nt] = __builtin_amdgcn_mfma_f32_16x16x32_f16(
              ah.h, bh[nt].h, hi[mt][nt], 0, 0, 0);
          cr[mt][nt] = __builtin_amdgcn_mfma_f32_16x16x32_f16(
              ah.h, bl[nt].h, cr[mt][nt], 0, 0, 0);
          cr[mt][nt] = __builtin_amdgcn_mfma_f32_16x16x32_f16(
              al.h, bh[nt].h, cr[mt][nt], 0, 0, 0);
        }
      }
    }
  }

  // combine products
  float y[2][2][4];
#pragma unroll
  for (int mt = 0; mt < 2; ++mt)
#pragma unroll
    for (int nt = 0; nt < 2; ++nt)
#pragma unroll
      for (int rg = 0; rg < 4; ++rg)
        y[mt][nt][rg] = hi[mt][nt][rg] + cr[mt][nt][rg] * (1.0f / 2048.0f);

  // fused BN stats: per-channel sum / sumsq over this block's 64 rows
#pragma unroll
  for (int nt = 0; nt < 2; ++nt) {
    float s = 0.f, s2 = 0.f;
#pragma unroll
    for (int mt = 0; mt < 2; ++mt)
#pragma unroll
      for (int rg = 0; rg < 4; ++rg) {
        float v = y[mt][nt][rg];
        s += v; s2 += v * v;
      }
    s  += __shfl_xor(s, 16, 64);  s  += __shfl_xor(s, 32, 64);
    s2 += __shfl_xor(s2, 16, 64); s2 += __shfl_xor(s2, 32, 64);
    if (lane < 16) {
      int c = n0 + wn2 * 32 + nt * 16 + m16;
      atomicAdd(&Ssum[c], s);
      atomicAdd(&Ssq[c], s2);
    }
  }

  // store yG[c][row] via LDS transpose (coalesced 64B runs)
  __syncthreads();
  float* Yl = (float*)Ah;                // 64 x 68 floats (fits in Ah)
#pragma unroll
  for (int mt = 0; mt < 2; ++mt)
#pragma unroll
    for (int nt = 0; nt < 2; ++nt)
#pragma unroll
      for (int rg = 0; rg < 4; ++rg)
        Yl[(wn2 * 32 + nt * 16 + m16) * 68 + wm * 32 + mt * 16 + q * 4 + rg] =
            y[mt][nt][rg];
  __syncthreads();
  {
    int c = tid >> 2, seg = (tid & 3) * 16;
#pragma unroll
    for (int j = 0; j < 16; j += 4)
      *(float4*)&yG[(n0 + c) * 2048 + row0 + seg + j] =
          *(const float4*)&Yl[c * 68 + seg + j];
  }
}

// ------------------------------------------------------------------ ab ------
// grid 352: blocks 0..255 = ab GEMM (scale/shift computed inline from atomic
// sums); 256..351 = wsplit for w1..w3.
__global__ __launch_bounds__(256) void ab_kernel(
    const float* __restrict__ yG, const float* __restrict__ Ssum,
    const float* __restrict__ Ssq,
    const float* __restrict__ g0, const float* __restrict__ be0,
    const float* __restrict__ g1, const float* __restrict__ be1,
    const float* __restrict__ mask, const float* __restrict__ w0,
    const float* __restrict__ w1, const float* __restrict__ w2,
    const float* __restrict__ w3, uint32_t* __restrict__ wpk,
    float* __restrict__ a_arr, float* __restrict__ bb_arr)
{
  int bx = blockIdx.x;
  int tid = threadIdx.x;
  if (bx >= 256) {
    int e = (bx - 256) * 256 + tid;       // 0..24575 (L, k2, n)
    int L = e >> 13;
    int r = e & 8191;
    int k2 = r >> 7, n = r & 127;
    int k = k2 * 2;
    const float* w = (L == 0) ? w1 : (L == 1) ? w2 : w3;
    uint32_t hw, lw;
    split2(w[k * 128 + n], w[(k + 1) * 128 + n], hw, lw);
    wpk[L * 8192 + n * 64 + k2] = hw;
    wpk[24576 + L * 8192 + n * 64 + k2] = lw;
    return;
  }
  __shared__ float As[32 * 36];
  __shared__ float Ws[32 * 68];
  __shared__ float scs[384], shs[384];
  // scale/shift from fused-atomics stats (BN + gamma/beta fold)
  for (int c = tid; c < 384; c += 256) {
    float Sv = Ssum[c], S2v = Ssq[c];
    float mean = Sv * (1.f / 2048.f);
    float var  = S2v * (1.f / 2048.f) - mean * mean;
    float g  = (c < 256) ? g0[c] : g1[c - 256];
    float be = (c < 256) ? be0[c] : be1[c - 256];
    float sc = g / sqrtf(var + 1e-5f);
    scs[c] = sc;
    shs[c] = be - mean * sc;
  }
  __syncthreads();

  int rt = bx & 63, ct = bx >> 6;
  int row0 = rt * 32, n0 = ct * 64;
  int r4 = (tid >> 5) * 4;
  int n2 = (tid & 31) * 2;
  int scc = tid >> 3, srr4 = (tid & 7) * 4;
  int wnn8 = (tid & 7) * 8;
  const float* wbase = (n0 < 128) ? (w0 + n0) : (w0 + CCH * 128 + (n0 - 128));
  float4 mv = *(const float4*)(mask + row0 + srr4);

  float acc[4][2] = {{0.f, 0.f}};
#pragma unroll 1
  for (int c0 = 0; c0 < 384; c0 += 32) {
    int c = c0 + scc;
    float4 yv = *(const float4*)(yG + c * 2048 + row0 + srr4);
    float sc = scs[c], sh = shs[c];
    float4 wv0 = *(const float4*)(wbase + c * 128 + wnn8);
    float4 wv1 = *(const float4*)(wbase + c * 128 + wnn8 + 4);
    __syncthreads();
    float4 hv;
    hv.x = leaky(fmaf(yv.x, sc, sh)) * mv.x;
    hv.y = leaky(fmaf(yv.y, sc, sh)) * mv.y;
    hv.z = leaky(fmaf(yv.z, sc, sh)) * mv.z;
    hv.w = leaky(fmaf(yv.w, sc, sh)) * mv.w;
    *(float4*)&As[scc * 36 + srr4] = hv;
    *(float4*)&Ws[scc * 68 + wnn8] = wv0;
    *(float4*)&Ws[scc * 68 + wnn8 + 4] = wv1;
    __syncthreads();
#pragma unroll
    for (int cc = 0; cc < 32; ++cc) {
      float4 a = *(const float4*)&As[cc * 36 + r4];
      float2 w = *(const float2*)&Ws[cc * 68 + n2];
      acc[0][0] = fmaf(a.x, w.x, acc[0][0]); acc[0][1] = fmaf(a.x, w.y, acc[0][1]);
      acc[1][0] = fmaf(a.y, w.x, acc[1][0]); acc[1][1] = fmaf(a.y, w.y, acc[1][1]);
      acc[2][0] = fmaf(a.z, w.x, acc[2][0]); acc[2][1] = fmaf(a.z, w.y, acc[2][1]);
      acc[3][0] = fmaf(a.w, w.x, acc[3][0]); acc[3][1] = fmaf(a.w, w.y, acc[3][1]);
    }
  }
  float* dst; int nd;
  if (n0 < 128) { dst = a_arr; nd = n0; } else { dst = bb_arr; nd = n0 - 128; }
#pragma unroll
  for (int ri = 0; ri < 4; ++ri)
    *(float2*)&dst[(row0 + r4 + ri) * 128 + nd + n2] = make_float2(acc[ri][0], acc[ri][1]);
}

// ---------------------------------------------------------------- pair ------
// R14: grid (64,32) = one (i,b) per block, 64 j-rows, K=128.
// 512 thr = 8 waves organized 1m x 8n: wave wid owns N-cols [wid*16,wid*16+16)
// and ALL 64 M-rows. acc hi[4]+cr[4]=32 VGPR, single Wh/Wl frag (no
// double-buffer) -> natural ~65 VGPR, (512,6)=3 blk/CU without spill.
__global__ __launch_bounds__(512, 6) void pair_kernel(
    const float* __restrict__ a_arr, const float* __restrict__ bb_arr,
    const float* __restrict__ b0, const uint32_t* __restrict__ wpk,
    const float* __restrict__ b1, const float* __restrict__ b2,
    const float* __restrict__ b3,
    const float* __restrict__ w4, const float* __restrict__ b4,
    const float* __restrict__ w5, const float* __restrict__ b5,
    const float* __restrict__ mask, float* __restrict__ out)
{
  __shared__ uint32_t Ahs[64 * 68];
  __shared__ uint32_t Als[64 * 68];
  int i = blockIdx.x, b = blockIdx.y;
  int tid = threadIdx.x;
  int browp = i * BB + b;                 // output row (i,b) in (L*B)

  // ---- stage A = leaky(a_i + bb_j + b0), split to f16 hi/lo planes
  {
    int k8 = (tid & 15) * 8;              // same for both its (512 % 16 == 0)
    const float* ap = a_arr + browp * 128 + k8;
    const float* zp = b0 + k8;
    float az[8];
#pragma unroll
    for (int t = 0; t < 8; t += 4) {
      float4 av = *(const float4*)(ap + t);
      float4 zv = *(const float4*)(zp + t);
      az[t + 0] = av.x + zv.x; az[t + 1] = av.y + zv.y;
      az[t + 2] = av.z + zv.z; az[t + 3] = av.w + zv.w;
    }
#pragma unroll
    for (int it = 0; it < 2; ++it) {
      int r = (it * 512 + tid) >> 4;      // j row 0..63
      const float* bbp = bb_arr + (r * BB + b) * 128 + k8;
      float d[8];
#pragma unroll
      for (int t = 0; t < 8; t += 4) {
        float4 bv = *(const float4*)(bbp + t);
        d[t + 0] = leaky(az[t + 0] + bv.x);
        d[t + 1] = leaky(az[t + 1] + bv.y);
        d[t + 2] = leaky(az[t + 2] + bv.z);
        d[t + 3] = leaky(az[t + 3] + bv.w);
      }
      uint4 hq, lq;
      split2(d[0], d[1], hq.x, lq.x);
      split2(d[2], d[3], hq.y, lq.y);
      split2(d[4], d[5], hq.z, lq.z);
      split2(d[6], d[7], hq.w, lq.w);
      *(uint4*)&Ahs[r * 68 + k8 / 2] = hq;
      *(uint4*)&Als[r * 68 + k8 / 2] = lq;
    }
  }
  __syncthreads();

  int wid = __builtin_amdgcn_readfirstlane(tid >> 6);
  int lane = tid & 63;
  int m16 = lane & 15, q = lane >> 4;
  int wn16 = wid * 16;
  int wrow = wn16 + m16;                  // this lane's N column 0..127

  f32x4 hi[4], cr[4];

#pragma unroll 1
  for (int L = 0; L < 3; ++L) {
    const uint32_t* WhL = wpk + L * 8192;
    const uint32_t* WlL = wpk + 24576 + L * 8192;
    const float* Bv = (L == 0) ? b1 : (L == 1) ? b2 : b3;
#pragma unroll
    for (int mt = 0; mt < 4; ++mt) {
      hi[mt] = (f32x4){0.f, 0.f, 0.f, 0.f};
      cr[mt] = (f32x4){0.f, 0.f, 0.f, 0.f};
    }

#pragma unroll
    for (int ks = 0; ks < 4; ++ks) {
      int koff = ks * 16 + q * 4;
      F8 Wh, Wl;
      Wh.q = *(const uint4*)(WhL + wrow * 64 + koff);
      Wl.q = *(const uint4*)(WlL + wrow * 64 + koff);
#pragma unroll
      for (int mt = 0; mt < 4; ++mt) {
        int arow = mt * 16 + m16;
        F8 Ah, Al;
        Ah.q = *(const uint4*)&Ahs[arow * 68 + koff];
        Al.q = *(const uint4*)&Als[arow * 68 + koff];
        hi[mt] = __builtin_amdgcn_mfma_f32_16x16x32_f16(
            Ah.h, Wh.h, hi[mt], 0, 0, 0);
        cr[mt] = __builtin_amdgcn_mfma_f32_16x16x32_f16(
            Ah.h, Wl.h, cr[mt], 0, 0, 0);
        cr[mt] = __builtin_amdgcn_mfma_f32_16x16x32_f16(
            Al.h, Wh.h, cr[mt], 0, 0, 0);
      }
    }

    float bias = Bv[wrow];

    if (L < 2) {
      __syncthreads();
      int par = lane & 1;
      int colw = (wn16 + (m16 & ~1)) >> 1;
#pragma unroll
      for (int mt = 0; mt < 4; ++mt) {
#pragma unroll
        for (int rg = 0; rg < 4; ++rg) {
          float d = leaky(hi[mt][rg] + cr[mt][rg] * (1.0f / 2048.0f) + bias);
          float dn = __shfl_xor(d, 1, 64);
          float de = par ? dn : d;
          float do_ = par ? d : dn;
          uint32_t hw, lw;
          split2(de, do_, hw, lw);
          int row = mt * 16 + q * 4 + rg;
          if (par) Als[row * 68 + colw] = lw;
          else     Ahs[row * 68 + colw] = hw;
        }
      }
      __syncthreads();
    } else {
      // mean over j (this block holds all 64 j for its (i,b));
      // each lane sums its 16 rows, q-fold completes the 64-row sum per col
      float s = 0.f;
#pragma unroll
      for (int mt = 0; mt < 4; ++mt)
#pragma unroll
        for (int rg = 0; rg < 4; ++rg)
          s += leaky(hi[mt][rg] + cr[mt][rg] * (1.0f / 2048.0f) + bias);
      s += __shfl_xor(s, 16, 64);
      s += __shfl_xor(s, 32, 64);
      float mfac = (1.0f / 64.0f) * mask[browp];
      __syncthreads();
      float* scratch = (float*)Ahs;
      float* Pm = scratch;            // p vector (128)
      float* Tp = scratch + 128;      // 4 partial chunks x 128
      float* T4 = scratch + 640;      // leaky(p@w4+b4) (128)
      if (lane < 16) Pm[wrow] = s * mfac;
      __syncthreads();
      {
        int k = tid & 127, chh = tid >> 7;     // 4 chunks of 32 c
        const float* w4c = w4 + (chh * 32) * 128 + k;
        const float* pc = Pm + chh * 32;
        float t = 0.f;
#pragma unroll 8
        for (int c0 = 0; c0 < 32; c0 += 4) {
          float4 pv = *(const float4*)&pc[c0];
          t = fmaf(pv.x, w4c[(c0 + 0) * 128], t);
          t = fmaf(pv.y, w4c[(c0 + 1) * 128], t);
          t = fmaf(pv.z, w4c[(c0 + 2) * 128], t);
          t = fmaf(pv.w, w4c[(c0 + 3) * 128], t);
        }
        Tp[chh * 128 + k] = t;
      }
      __syncthreads();
      if (tid < 128)
        T4[tid] = leaky(Tp[tid] + Tp[128 + tid] + Tp[256 + tid] +
                        Tp[384 + tid] + b4[tid]);
      __syncthreads();
      {
        float o = b5[tid];
#pragma unroll 4
        for (int c0 = 0; c0 < 128; c0 += 4) {
          float4 tv = *(const float4*)&T4[c0];
          o = fmaf(tv.x, w5[(c0 + 0) * 512 + tid], o);
          o = fmaf(tv.y, w5[(c0 + 1) * 512 + tid], o);
          o = fmaf(tv.z, w5[(c0 + 2) * 512 + tid], o);
          o = fmaf(tv.w, w5[(c0 + 3) * 512 + tid], o);
        }
        out[browp * 512 + tid] = leaky(o) * mask[browp];
      }
    }
  }
}

// -------------------------------------------------------------- launch ------
extern "C" void kernel_launch(void* const* d_in, const int* in_sizes, int n_in,
                              void* d_out, int out_size, void* d_ws, size_t ws_size,
                              hipStream_t stream) {
  const float* x    = (const float*)d_in[0];
  const float* mask = (const float*)d_in[1];
  const float* cw0  = (const float*)d_in[2];
  // d_in[3] conv_b0: cancels in BN
  const float* g0   = (const float*)d_in[4];
  const float* be0  = (const float*)d_in[5];
  const float* cw1  = (const float*)d_in[6];
  // d_in[7] conv_b1: cancels in BN
  const float* g1   = (const float*)d_in[8];
  const float* be1  = (const float*)d_in[9];
  const float* w0   = (const float*)d_in[10];
  const float* b0   = (const float*)d_in[11];
  const float* w1   = (const float*)d_in[12];
  const float* b1   = (const float*)d_in[13];
  const float* w2   = (const float*)d_in[14];
  const float* b2   = (const float*)d_in[15];
  const float* w3   = (const float*)d_in[16];
  const float* b3   = (const float*)d_in[17];
  const float* w4   = (const float*)d_in[18];
  const float* b4   = (const float*)d_in[19];
  const float* w5   = (const float*)d_in[20];
  const float* b5   = (const float*)d_in[21];

  float* ws     = (float*)d_ws;
  float* Ssum   = ws;                         // 384
  float* Ssq    = ws + 384;                   // 384
  float* yG     = ws + 768;                   // 384*2048 = 786432
  uint32_t* wpk = (uint32_t*)(ws + 787200);   // 49152
  float* a_arr  = ws + 836352;                // 2048*128
  float* bb_arr = ws + 1098496;               // 2048*128
  float* outp   = (float*)d_out;

  hipMemsetAsync(Ssum, 0, 768 * sizeof(float), stream);
  conv_kernel<<<192, 256, 0, stream>>>(x, mask, cw0, cw1, yG, Ssum, Ssq);
  ab_kernel<<<352, 256, 0, stream>>>(yG, Ssum, Ssq, g0, be0, g1, be1,
                                     mask, w0, w1, w2, w3, wpk, a_arr, bb_arr);
  dim3 g5(64, 32);
  pair_kernel<<<g5, 512, 0, stream>>>(a_arr, bb_arr, b0, wpk, b1, b2, b3,
                                      w4, b4, w5, b5, mask, outp);
}

// Round 3
// 279.412 us; speedup vs baseline: 1.5073x; 1.4029x over previous
//
#include <hip/hip_runtime.h>

// RelationLayer, round 15.
// R13/R14 both spilled with VGPR_Count=40: backwards arithmetic (512/40 ~ 12
// waves/SIMD = 6 blocks/CU) shows THIS hipcc treats __launch_bounds__ arg2 as
// CUDA-style min-BLOCKS-per-CU, not waves-per-EU. "(512,6)" demanded 6
// resident blocks -> 40-VGPR cap -> 250MB/launch scratch spill. R12 (no arg2)
// = 96 VGPR, no spill, confirms.
// R15: ONE change vs R14 -- __launch_bounds__(512, 3): 3 blocks/CU x 8 waves
// = 6 waves/SIMD -> ~84 VGPR budget, which R14's slim 1m x 8n structure
// (acc 32 + single Wh/Wl frag pair) fits without spill. LDS 34.8KB x 3 =
// 104KB <= 160KB. conv/ab unchanged.

#define BB 32
#define CCH 384

__device__ __forceinline__ float leaky(float x) { return fmaxf(x, 0.1f * x); }

typedef _Float16 f16x8 __attribute__((ext_vector_type(8)));
typedef float f32x4 __attribute__((ext_vector_type(4)));

union F8 { uint4 q; f16x8 h; };
union H2 { _Float16 f[2]; uint32_t u; };

__device__ __forceinline__ void split2(float d0, float d1,
                                       uint32_t& hw, uint32_t& lw) {
  H2 h, l;
  h.f[0] = (_Float16)d0; h.f[1] = (_Float16)d1;
  l.f[0] = (_Float16)((d0 - (float)h.f[0]) * 2048.0f);
  l.f[1] = (_Float16)((d1 - (float)h.f[1]) * 2048.0f);
  hw = h.u; lw = l.u;
}

// ---------------------------------------------------------------- conv ------
// grid 192 = 32 m-tiles(64 rows) x 6 n-tiles(64 ch): nb 0..3 win1 (K=512),
// nb 4..5 win3 (K=1536, taps in-K). Output yG[c][row] recombined, c<384.
__global__ __launch_bounds__(256) void conv_kernel(
    const float* __restrict__ x, const float* __restrict__ mask,
    const float* __restrict__ cw0, const float* __restrict__ cw1,
    float* __restrict__ yG, float* __restrict__ Ssum, float* __restrict__ Ssq)
{
  __shared__ uint32_t Ah[64 * 68], Al[64 * 68];
  __shared__ uint32_t Bh[64 * 68], Bl[64 * 68];
  int bx = blockIdx.x;
  int nb = bx % 6, mb = bx / 6;
  int n0 = nb * 64;
  int row0 = mb * 64;
  bool w3 = (nb >= 4);
  int nch = w3 ? 12 : 4;
  const float* wbase = w3 ? (cw1 + (n0 - 256) * 1536) : (cw0 + n0 * 512);
  int wK = w3 ? 1536 : 512;

  int tid = threadIdx.x;
  int wid = __builtin_amdgcn_readfirstlane(tid >> 6);
  int wm = wid & 1, wn2 = wid >> 1;
  int lane = tid & 63;
  int m16 = lane & 15, q = lane >> 4;

  f32x4 hi[2][2], cr[2][2];
#pragma unroll
  for (int a = 0; a < 2; ++a)
#pragma unroll
    for (int b = 0; b < 2; ++b) {
      hi[a][b] = (f32x4){0.f, 0.f, 0.f, 0.f};
      cr[a][b] = (f32x4){0.f, 0.f, 0.f, 0.f};
    }

#pragma unroll 1
  for (int ch = 0; ch < nch; ++ch) {
    int kg0 = ch * 128;
    int tap = kg0 >> 9;
    int d0 = kg0 & 511;
    int shift = w3 ? (tap - 1) * 32 : 0;
    __syncthreads();                     // prior chunk's frag reads done
#pragma unroll 1
    for (int it = 0; it < 4; ++it) {
      int idx = it * 256 + tid;
      int r = idx >> 4;                  // 0..63
      int k8 = (idx & 15) * 8;           // 0..120
      // A: x * mask, row-shifted per tap, zero-padded at edges
      float d[8];
      int rowg = row0 + r + shift;
      if ((unsigned)rowg < 2048u) {
        float mv = mask[rowg];
        const float* xp = x + rowg * 512 + d0 + k8;
        float4 a0 = *(const float4*)xp;
        float4 a1 = *(const float4*)(xp + 4);
        d[0] = a0.x * mv; d[1] = a0.y * mv; d[2] = a0.z * mv; d[3] = a0.w * mv;
        d[4] = a1.x * mv; d[5] = a1.y * mv; d[6] = a1.z * mv; d[7] = a1.w * mv;
      } else {
#pragma unroll
        for (int t2 = 0; t2 < 8; ++t2) d[t2] = 0.f;
      }
      uint4 hq, lq;
      split2(d[0], d[1], hq.x, lq.x);
      split2(d[2], d[3], hq.y, lq.y);
      split2(d[4], d[5], hq.z, lq.z);
      split2(d[6], d[7], hq.w, lq.w);
      *(uint4*)&Ah[r * 68 + k8 / 2] = hq;
      *(uint4*)&Al[r * 68 + k8 / 2] = lq;
      // B: conv weights (cw1 k-layout is already tap-major -> direct)
      const float* wp = wbase + r * wK + kg0 + k8;
      float4 b0v = *(const float4*)wp;
      float4 b1v = *(const float4*)(wp + 4);
      split2(b0v.x, b0v.y, hq.x, lq.x);
      split2(b0v.z, b0v.w, hq.y, lq.y);
      split2(b1v.x, b1v.y, hq.z, lq.z);
      split2(b1v.z, b1v.w, hq.w, lq.w);
      *(uint4*)&Bh[r * 68 + k8 / 2] = hq;
      *(uint4*)&Bl[r * 68 + k8 / 2] = lq;
    }
    __syncthreads();
#pragma unroll
    for (int ks = 0; ks < 4; ++ks) {
      int koff = ks * 16 + q * 4;
      F8 bh[2], bl[2];
#pragma unroll
      for (int nt = 0; nt < 2; ++nt) {
        int br = wn2 * 32 + nt * 16 + m16;
        bh[nt].q = *(const uint4*)&Bh[br * 68 + koff];
        bl[nt].q = *(const uint4*)&Bl[br * 68 + koff];
      }
#pragma unroll
      for (int mt = 0; mt < 2; ++mt) {
        int ar = wm * 32 + mt * 16 + m16;
        F8 ah, al;
        ah.q = *(const uint4*)&Ah[ar * 68 + koff];
        al.q = *(const uint4*)&Al[ar * 68 + koff];
#pragma unroll
        for (int nt = 0; nt < 2; ++nt) {
          hi[mt][nt] = __builtin_amdgcn_mfma_f32_16x16x32_f16(
              ah.h, bh[nt].h, hi[mt][nt], 0, 0, 0);
          cr[mt][nt] = __builtin_amdgcn_mfma_f32_16x16x32_f16(
              ah.h, bl[nt].h, cr[mt][nt], 0, 0, 0);
          cr[mt][nt] = __builtin_amdgcn_mfma_f32_16x16x32_f16(
              al.h, bh[nt].h, cr[mt][nt], 0, 0, 0);
        }
      }
    }
  }

  // combine products
  float y[2][2][4];
#pragma unroll
  for (int mt = 0; mt < 2; ++mt)
#pragma unroll
    for (int nt = 0; nt < 2; ++nt)
#pragma unroll
      for (int rg = 0; rg < 4; ++rg)
        y[mt][nt][rg] = hi[mt][nt][rg] + cr[mt][nt][rg] * (1.0f / 2048.0f);

  // fused BN stats: per-channel sum / sumsq over this block's 64 rows
#pragma unroll
  for (int nt = 0; nt < 2; ++nt) {
    float s = 0.f, s2 = 0.f;
#pragma unroll
    for (int mt = 0; mt < 2; ++mt)
#pragma unroll
      for (int rg = 0; rg < 4; ++rg) {
        float v = y[mt][nt][rg];
        s += v; s2 += v * v;
      }
    s  += __shfl_xor(s, 16, 64);  s  += __shfl_xor(s, 32, 64);
    s2 += __shfl_xor(s2, 16, 64); s2 += __shfl_xor(s2, 32, 64);
    if (lane < 16) {
      int c = n0 + wn2 * 32 + nt * 16 + m16;
      atomicAdd(&Ssum[c], s);
      atomicAdd(&Ssq[c], s2);
    }
  }

  // store yG[c][row] via LDS transpose (coalesced 64B runs)
  __syncthreads();
  float* Yl = (float*)Ah;                // 64 x 68 floats (fits in Ah)
#pragma unroll
  for (int mt = 0; mt < 2; ++mt)
#pragma unroll
    for (int nt = 0; nt < 2; ++nt)
#pragma unroll
      for (int rg = 0; rg < 4; ++rg)
        Yl[(wn2 * 32 + nt * 16 + m16) * 68 + wm * 32 + mt * 16 + q * 4 + rg] =
            y[mt][nt][rg];
  __syncthreads();
  {
    int c = tid >> 2, seg = (tid & 3) * 16;
#pragma unroll
    for (int j = 0; j < 16; j += 4)
      *(float4*)&yG[(n0 + c) * 2048 + row0 + seg + j] =
          *(const float4*)&Yl[c * 68 + seg + j];
  }
}

// ------------------------------------------------------------------ ab ------
// grid 352: blocks 0..255 = ab GEMM (scale/shift computed inline from atomic
// sums); 256..351 = wsplit for w1..w3.
__global__ __launch_bounds__(256) void ab_kernel(
    const float* __restrict__ yG, const float* __restrict__ Ssum,
    const float* __restrict__ Ssq,
    const float* __restrict__ g0, const float* __restrict__ be0,
    const float* __restrict__ g1, const float* __restrict__ be1,
    const float* __restrict__ mask, const float* __restrict__ w0,
    const float* __restrict__ w1, const float* __restrict__ w2,
    const float* __restrict__ w3, uint32_t* __restrict__ wpk,
    float* __restrict__ a_arr, float* __restrict__ bb_arr)
{
  int bx = blockIdx.x;
  int tid = threadIdx.x;
  if (bx >= 256) {
    int e = (bx - 256) * 256 + tid;       // 0..24575 (L, k2, n)
    int L = e >> 13;
    int r = e & 8191;
    int k2 = r >> 7, n = r & 127;
    int k = k2 * 2;
    const float* w = (L == 0) ? w1 : (L == 1) ? w2 : w3;
    uint32_t hw, lw;
    split2(w[k * 128 + n], w[(k + 1) * 128 + n], hw, lw);
    wpk[L * 8192 + n * 64 + k2] = hw;
    wpk[24576 + L * 8192 + n * 64 + k2] = lw;
    return;
  }
  __shared__ float As[32 * 36];
  __shared__ float Ws[32 * 68];
  __shared__ float scs[384], shs[384];
  // scale/shift from fused-atomics stats (BN + gamma/beta fold)
  for (int c = tid; c < 384; c += 256) {
    float Sv = Ssum[c], S2v = Ssq[c];
    float mean = Sv * (1.f / 2048.f);
    float var  = S2v * (1.f / 2048.f) - mean * mean;
    float g  = (c < 256) ? g0[c] : g1[c - 256];
    float be = (c < 256) ? be0[c] : be1[c - 256];
    float sc = g / sqrtf(var + 1e-5f);
    scs[c] = sc;
    shs[c] = be - mean * sc;
  }
  __syncthreads();

  int rt = bx & 63, ct = bx >> 6;
  int row0 = rt * 32, n0 = ct * 64;
  int r4 = (tid >> 5) * 4;
  int n2 = (tid & 31) * 2;
  int scc = tid >> 3, srr4 = (tid & 7) * 4;
  int wnn8 = (tid & 7) * 8;
  const float* wbase = (n0 < 128) ? (w0 + n0) : (w0 + CCH * 128 + (n0 - 128));
  float4 mv = *(const float4*)(mask + row0 + srr4);

  float acc[4][2] = {{0.f, 0.f}};
#pragma unroll 1
  for (int c0 = 0; c0 < 384; c0 += 32) {
    int c = c0 + scc;
    float4 yv = *(const float4*)(yG + c * 2048 + row0 + srr4);
    float sc = scs[c], sh = shs[c];
    float4 wv0 = *(const float4*)(wbase + c * 128 + wnn8);
    float4 wv1 = *(const float4*)(wbase + c * 128 + wnn8 + 4);
    __syncthreads();
    float4 hv;
    hv.x = leaky(fmaf(yv.x, sc, sh)) * mv.x;
    hv.y = leaky(fmaf(yv.y, sc, sh)) * mv.y;
    hv.z = leaky(fmaf(yv.z, sc, sh)) * mv.z;
    hv.w = leaky(fmaf(yv.w, sc, sh)) * mv.w;
    *(float4*)&As[scc * 36 + srr4] = hv;
    *(float4*)&Ws[scc * 68 + wnn8] = wv0;
    *(float4*)&Ws[scc * 68 + wnn8 + 4] = wv1;
    __syncthreads();
#pragma unroll
    for (int cc = 0; cc < 32; ++cc) {
      float4 a = *(const float4*)&As[cc * 36 + r4];
      float2 w = *(const float2*)&Ws[cc * 68 + n2];
      acc[0][0] = fmaf(a.x, w.x, acc[0][0]); acc[0][1] = fmaf(a.x, w.y, acc[0][1]);
      acc[1][0] = fmaf(a.y, w.x, acc[1][0]); acc[1][1] = fmaf(a.y, w.y, acc[1][1]);
      acc[2][0] = fmaf(a.z, w.x, acc[2][0]); acc[2][1] = fmaf(a.z, w.y, acc[2][1]);
      acc[3][0] = fmaf(a.w, w.x, acc[3][0]); acc[3][1] = fmaf(a.w, w.y, acc[3][1]);
    }
  }
  float* dst; int nd;
  if (n0 < 128) { dst = a_arr; nd = n0; } else { dst = bb_arr; nd = n0 - 128; }
#pragma unroll
  for (int ri = 0; ri < 4; ++ri)
    *(float2*)&dst[(row0 + r4 + ri) * 128 + nd + n2] = make_float2(acc[ri][0], acc[ri][1]);
}

// ---------------------------------------------------------------- pair ------
// R15: grid (64,32) = one (i,b) per block, 64 j-rows, K=128.
// 512 thr = 8 waves organized 1m x 8n: wave wid owns N-cols [wid*16,wid*16+16)
// and ALL 64 M-rows. launch_bounds(512,3) = 3 BLOCKS/CU (CUDA semantics,
// confirmed by R13/R14's 40-VGPR cap at arg2=6) -> ~84 VGPR budget.
__global__ __launch_bounds__(512, 3) void pair_kernel(
    const float* __restrict__ a_arr, const float* __restrict__ bb_arr,
    const float* __restrict__ b0, const uint32_t* __restrict__ wpk,
    const float* __restrict__ b1, const float* __restrict__ b2,
    const float* __restrict__ b3,
    const float* __restrict__ w4, const float* __restrict__ b4,
    const float* __restrict__ w5, const float* __restrict__ b5,
    const float* __restrict__ mask, float* __restrict__ out)
{
  __shared__ uint32_t Ahs[64 * 68];
  __shared__ uint32_t Als[64 * 68];
  int i = blockIdx.x, b = blockIdx.y;
  int tid = threadIdx.x;
  int browp = i * BB + b;                 // output row (i,b) in (L*B)

  // ---- stage A = leaky(a_i + bb_j + b0), split to f16 hi/lo planes
  {
    int k8 = (tid & 15) * 8;              // same for both its (512 % 16 == 0)
    const float* ap = a_arr + browp * 128 + k8;
    const float* zp = b0 + k8;
    float az[8];
#pragma unroll
    for (int t = 0; t < 8; t += 4) {
      float4 av = *(const float4*)(ap + t);
      float4 zv = *(const float4*)(zp + t);
      az[t + 0] = av.x + zv.x; az[t + 1] = av.y + zv.y;
      az[t + 2] = av.z + zv.z; az[t + 3] = av.w + zv.w;
    }
#pragma unroll
    for (int it = 0; it < 2; ++it) {
      int r = (it * 512 + tid) >> 4;      // j row 0..63
      const float* bbp = bb_arr + (r * BB + b) * 128 + k8;
      float d[8];
#pragma unroll
      for (int t = 0; t < 8; t += 4) {
        float4 bv = *(const float4*)(bbp + t);
        d[t + 0] = leaky(az[t + 0] + bv.x);
        d[t + 1] = leaky(az[t + 1] + bv.y);
        d[t + 2] = leaky(az[t + 2] + bv.z);
        d[t + 3] = leaky(az[t + 3] + bv.w);
      }
      uint4 hq, lq;
      split2(d[0], d[1], hq.x, lq.x);
      split2(d[2], d[3], hq.y, lq.y);
      split2(d[4], d[5], hq.z, lq.z);
      split2(d[6], d[7], hq.w, lq.w);
      *(uint4*)&Ahs[r * 68 + k8 / 2] = hq;
      *(uint4*)&Als[r * 68 + k8 / 2] = lq;
    }
  }
  __syncthreads();

  int wid = __builtin_amdgcn_readfirstlane(tid >> 6);
  int lane = tid & 63;
  int m16 = lane & 15, q = lane >> 4;
  int wn16 = wid * 16;
  int wrow = wn16 + m16;                  // this lane's N column 0..127

  f32x4 hi[4], cr[4];

#pragma unroll 1
  for (int L = 0; L < 3; ++L) {
    const uint32_t* WhL = wpk + L * 8192;
    const uint32_t* WlL = wpk + 24576 + L * 8192;
    const float* Bv = (L == 0) ? b1 : (L == 1) ? b2 : b3;
#pragma unroll
    for (int mt = 0; mt < 4; ++mt) {
      hi[mt] = (f32x4){0.f, 0.f, 0.f, 0.f};
      cr[mt] = (f32x4){0.f, 0.f, 0.f, 0.f};
    }

#pragma unroll
    for (int ks = 0; ks < 4; ++ks) {
      int koff = ks * 16 + q * 4;
      F8 Wh, Wl;
      Wh.q = *(const uint4*)(WhL + wrow * 64 + koff);
      Wl.q = *(const uint4*)(WlL + wrow * 64 + koff);
#pragma unroll
      for (int mt = 0; mt < 4; ++mt) {
        int arow = mt * 16 + m16;
        F8 Ah, Al;
        Ah.q = *(const uint4*)&Ahs[arow * 68 + koff];
        Al.q = *(const uint4*)&Als[arow * 68 + koff];
        hi[mt] = __builtin_amdgcn_mfma_f32_16x16x32_f16(
            Ah.h, Wh.h, hi[mt], 0, 0, 0);
        cr[mt] = __builtin_amdgcn_mfma_f32_16x16x32_f16(
            Ah.h, Wl.h, cr[mt], 0, 0, 0);
        cr[mt] = __builtin_amdgcn_mfma_f32_16x16x32_f16(
            Al.h, Wh.h, cr[mt], 0, 0, 0);
      }
    }

    float bias = Bv[wrow];

    if (L < 2) {
      __syncthreads();
      int par = lane & 1;
      int colw = (wn16 + (m16 & ~1)) >> 1;
#pragma unroll
      for (int mt = 0; mt < 4; ++mt) {
#pragma unroll
        for (int rg = 0; rg < 4; ++rg) {
          float d = leaky(hi[mt][rg] + cr[mt][rg] * (1.0f / 2048.0f) + bias);
          float dn = __shfl_xor(d, 1, 64);
          float de = par ? dn : d;
          float do_ = par ? d : dn;
          uint32_t hw, lw;
          split2(de, do_, hw, lw);
          int row = mt * 16 + q * 4 + rg;
          if (par) Als[row * 68 + colw] = lw;
          else     Ahs[row * 68 + colw] = hw;
        }
      }
      __syncthreads();
    } else {
      // mean over j (this block holds all 64 j for its (i,b));
      // each lane sums its 16 rows, q-fold completes the 64-row sum per col
      float s = 0.f;
#pragma unroll
      for (int mt = 0; mt < 4; ++mt)
#pragma unroll
        for (int rg = 0; rg < 4; ++rg)
          s += leaky(hi[mt][rg] + cr[mt][rg] * (1.0f / 2048.0f) + bias);
      s += __shfl_xor(s, 16, 64);
      s += __shfl_xor(s, 32, 64);
      float mfac = (1.0f / 64.0f) * mask[browp];
      __syncthreads();
      float* scratch = (float*)Ahs;
      float* Pm = scratch;            // p vector (128)
      float* Tp = scratch + 128;      // 4 partial chunks x 128
      float* T4 = scratch + 640;      // leaky(p@w4+b4) (128)
      if (lane < 16) Pm[wrow] = s * mfac;
      __syncthreads();
      {
        int k = tid & 127, chh = tid >> 7;     // 4 chunks of 32 c
        const float* w4c = w4 + (chh * 32) * 128 + k;
        const float* pc = Pm + chh * 32;
        float t = 0.f;
#pragma unroll 8
        for (int c0 = 0; c0 < 32; c0 += 4) {
          float4 pv = *(const float4*)&pc[c0];
          t = fmaf(pv.x, w4c[(c0 + 0) * 128], t);
          t = fmaf(pv.y, w4c[(c0 + 1) * 128], t);
          t = fmaf(pv.z, w4c[(c0 + 2) * 128], t);
          t = fmaf(pv.w, w4c[(c0 + 3) * 128], t);
        }
        Tp[chh * 128 + k] = t;
      }
      __syncthreads();
      if (tid < 128)
        T4[tid] = leaky(Tp[tid] + Tp[128 + tid] + Tp[256 + tid] +
                        Tp[384 + tid] + b4[tid]);
      __syncthreads();
      {
        float o = b5[tid];
#pragma unroll 4
        for (int c0 = 0; c0 < 128; c0 += 4) {
          float4 tv = *(const float4*)&T4[c0];
          o = fmaf(tv.x, w5[(c0 + 0) * 512 + tid], o);
          o = fmaf(tv.y, w5[(c0 + 1) * 512 + tid], o);
          o = fmaf(tv.z, w5[(c0 + 2) * 512 + tid], o);
          o = fmaf(tv.w, w5[(c0 + 3) * 512 + tid], o);
        }
        out[browp * 512 + tid] = leaky(o) * mask[browp];
      }
    }
  }
}

// -------------------------------------------------------------- launch ------
extern "C" void kernel_launch(void* const* d_in, const int* in_sizes, int n_in,
                              void* d_out, int out_size, void* d_ws, size_t ws_size,
                              hipStream_t stream) {
  const float* x    = (const float*)d_in[0];
  const float* mask = (const float*)d_in[1];
  const float* cw0  = (const float*)d_in[2];
  // d_in[3] conv_b0: cancels in BN
  const float* g0   = (const float*)d_in[4];
  const float* be0  = (const float*)d_in[5];
  const float* cw1  = (const float*)d_in[6];
  // d_in[7] conv_b1: cancels in BN
  const float* g1   = (const float*)d_in[8];
  const float* be1  = (const float*)d_in[9];
  const float* w0   = (const float*)d_in[10];
  const float* b0   = (const float*)d_in[11];
  const float* w1   = (const float*)d_in[12];
  const float* b1   = (const float*)d_in[13];
  const float* w2   = (const float*)d_in[14];
  const float* b2   = (const float*)d_in[15];
  const float* w3   = (const float*)d_in[16];
  const float* b3   = (const float*)d_in[17];
  const float* w4   = (const float*)d_in[18];
  const float* b4   = (const float*)d_in[19];
  const float* w5   = (const float*)d_in[20];
  const float* b5   = (const float*)d_in[21];

  float* ws     = (float*)d_ws;
  float* Ssum   = ws;                         // 384
  float* Ssq    = ws + 384;                   // 384
  float* yG     = ws + 768;                   // 384*2048 = 786432
  uint32_t* wpk = (uint32_t*)(ws + 787200);   // 49152
  float* a_arr  = ws + 836352;                // 2048*128
  float* bb_arr = ws + 1098496;               // 2048*128
  float* outp   = (float*)d_out;

  hipMemsetAsync(Ssum, 0, 768 * sizeof(float), stream);
  conv_kernel<<<192, 256, 0, stream>>>(x, mask, cw0, cw1, yG, Ssum, Ssq);
  ab_kernel<<<352, 256, 0, stream>>>(yG, Ssum, Ssq, g0, be0, g1, be1,
                                     mask, w0, w1, w2, w3, wpk, a_arr, bb_arr);
  dim3 g5(64, 32);
  pair_kernel<<<g5, 512, 0, stream>>>(a_arr, bb_arr, b0, wpk, b1, b2, b3,
                                      w4, b4, w5, b5, mask, outp);
}

// Round 4
// 267.846 us; speedup vs baseline: 1.5724x; 1.0432x over previous
//
#include <hip/hip_runtime.h>

// RelationLayer, round 16.
// R15 = 279us, pair 137us (slower than R12's 114): spill fixed (VGPR 76,
// FETCH 6.7MB) but R15 dropped R12's weight double-buffer -- Wh/Wl loaded
// from global (L2) INSIDE the ks loop, 4 serial ~200cy round-trips per
// layer per wave on the critical path (MfmaUtil 11.5, VALU 27, HBM 1% =
// latency-bound).
// R16: restore ks-level weight double-buffer in the slim R15 structure,
// with cross-layer hoist: (L+1,ks0) weights issued after last MFMA of L
// (hides under rewrite), (0,0) issued before A-staging (hides under
// staging). Natural VGPR ~84-90; launch_bounds(512,3) caps ~85 -> 3
// blocks/CU, 24 waves/CU. TRIPWIRE: FETCH_SIZE >50MB = forced spill ->
// revert to (512,2) next round. conv/ab unchanged.

#define BB 32
#define CCH 384

__device__ __forceinline__ float leaky(float x) { return fmaxf(x, 0.1f * x); }

typedef _Float16 f16x8 __attribute__((ext_vector_type(8)));
typedef float f32x4 __attribute__((ext_vector_type(4)));

union F8 { uint4 q; f16x8 h; };
union H2 { _Float16 f[2]; uint32_t u; };

__device__ __forceinline__ void split2(float d0, float d1,
                                       uint32_t& hw, uint32_t& lw) {
  H2 h, l;
  h.f[0] = (_Float16)d0; h.f[1] = (_Float16)d1;
  l.f[0] = (_Float16)((d0 - (float)h.f[0]) * 2048.0f);
  l.f[1] = (_Float16)((d1 - (float)h.f[1]) * 2048.0f);
  hw = h.u; lw = l.u;
}

// ---------------------------------------------------------------- conv ------
// grid 192 = 32 m-tiles(64 rows) x 6 n-tiles(64 ch): nb 0..3 win1 (K=512),
// nb 4..5 win3 (K=1536, taps in-K). Output yG[c][row] recombined, c<384.
__global__ __launch_bounds__(256) void conv_kernel(
    const float* __restrict__ x, const float* __restrict__ mask,
    const float* __restrict__ cw0, const float* __restrict__ cw1,
    float* __restrict__ yG, float* __restrict__ Ssum, float* __restrict__ Ssq)
{
  __shared__ uint32_t Ah[64 * 68], Al[64 * 68];
  __shared__ uint32_t Bh[64 * 68], Bl[64 * 68];
  int bx = blockIdx.x;
  int nb = bx % 6, mb = bx / 6;
  int n0 = nb * 64;
  int row0 = mb * 64;
  bool w3 = (nb >= 4);
  int nch = w3 ? 12 : 4;
  const float* wbase = w3 ? (cw1 + (n0 - 256) * 1536) : (cw0 + n0 * 512);
  int wK = w3 ? 1536 : 512;

  int tid = threadIdx.x;
  int wid = __builtin_amdgcn_readfirstlane(tid >> 6);
  int wm = wid & 1, wn2 = wid >> 1;
  int lane = tid & 63;
  int m16 = lane & 15, q = lane >> 4;

  f32x4 hi[2][2], cr[2][2];
#pragma unroll
  for (int a = 0; a < 2; ++a)
#pragma unroll
    for (int b = 0; b < 2; ++b) {
      hi[a][b] = (f32x4){0.f, 0.f, 0.f, 0.f};
      cr[a][b] = (f32x4){0.f, 0.f, 0.f, 0.f};
    }

#pragma unroll 1
  for (int ch = 0; ch < nch; ++ch) {
    int kg0 = ch * 128;
    int tap = kg0 >> 9;
    int d0 = kg0 & 511;
    int shift = w3 ? (tap - 1) * 32 : 0;
    __syncthreads();                     // prior chunk's frag reads done
#pragma unroll 1
    for (int it = 0; it < 4; ++it) {
      int idx = it * 256 + tid;
      int r = idx >> 4;                  // 0..63
      int k8 = (idx & 15) * 8;           // 0..120
      // A: x * mask, row-shifted per tap, zero-padded at edges
      float d[8];
      int rowg = row0 + r + shift;
      if ((unsigned)rowg < 2048u) {
        float mv = mask[rowg];
        const float* xp = x + rowg * 512 + d0 + k8;
        float4 a0 = *(const float4*)xp;
        float4 a1 = *(const float4*)(xp + 4);
        d[0] = a0.x * mv; d[1] = a0.y * mv; d[2] = a0.z * mv; d[3] = a0.w * mv;
        d[4] = a1.x * mv; d[5] = a1.y * mv; d[6] = a1.z * mv; d[7] = a1.w * mv;
      } else {
#pragma unroll
        for (int t2 = 0; t2 < 8; ++t2) d[t2] = 0.f;
      }
      uint4 hq, lq;
      split2(d[0], d[1], hq.x, lq.x);
      split2(d[2], d[3], hq.y, lq.y);
      split2(d[4], d[5], hq.z, lq.z);
      split2(d[6], d[7], hq.w, lq.w);
      *(uint4*)&Ah[r * 68 + k8 / 2] = hq;
      *(uint4*)&Al[r * 68 + k8 / 2] = lq;
      // B: conv weights (cw1 k-layout is already tap-major -> direct)
      const float* wp = wbase + r * wK + kg0 + k8;
      float4 b0v = *(const float4*)wp;
      float4 b1v = *(const float4*)(wp + 4);
      split2(b0v.x, b0v.y, hq.x, lq.x);
      split2(b0v.z, b0v.w, hq.y, lq.y);
      split2(b1v.x, b1v.y, hq.z, lq.z);
      split2(b1v.z, b1v.w, hq.w, lq.w);
      *(uint4*)&Bh[r * 68 + k8 / 2] = hq;
      *(uint4*)&Bl[r * 68 + k8 / 2] = lq;
    }
    __syncthreads();
#pragma unroll
    for (int ks = 0; ks < 4; ++ks) {
      int koff = ks * 16 + q * 4;
      F8 bh[2], bl[2];
#pragma unroll
      for (int nt = 0; nt < 2; ++nt) {
        int br = wn2 * 32 + nt * 16 + m16;
        bh[nt].q = *(const uint4*)&Bh[br * 68 + koff];
        bl[nt].q = *(const uint4*)&Bl[br * 68 + koff];
      }
#pragma unroll
      for (int mt = 0; mt < 2; ++mt) {
        int ar = wm * 32 + mt * 16 + m16;
        F8 ah, al;
        ah.q = *(const uint4*)&Ah[ar * 68 + koff];
        al.q = *(const uint4*)&Al[ar * 68 + koff];
#pragma unroll
        for (int nt = 0; nt < 2; ++nt) {
          hi[mt][nt] = __builtin_amdgcn_mfma_f32_16x16x32_f16(
              ah.h, bh[nt].h, hi[mt][nt], 0, 0, 0);
          cr[mt][nt] = __builtin_amdgcn_mfma_f32_16x16x32_f16(
              ah.h, bl[nt].h, cr[mt][nt], 0, 0, 0);
          cr[mt][nt] = __builtin_amdgcn_mfma_f32_16x16x32_f16(
              al.h, bh[nt].h, cr[mt][nt], 0, 0, 0);
        }
      }
    }
  }

  // combine products
  float y[2][2][4];
#pragma unroll
  for (int mt = 0; mt < 2; ++mt)
#pragma unroll
    for (int nt = 0; nt < 2; ++nt)
#pragma unroll
      for (int rg = 0; rg < 4; ++rg)
        y[mt][nt][rg] = hi[mt][nt][rg] + cr[mt][nt][rg] * (1.0f / 2048.0f);

  // fused BN stats: per-channel sum / sumsq over this block's 64 rows
#pragma unroll
  for (int nt = 0; nt < 2; ++nt) {
    float s = 0.f, s2 = 0.f;
#pragma unroll
    for (int mt = 0; mt < 2; ++mt)
#pragma unroll
      for (int rg = 0; rg < 4; ++rg) {
        float v = y[mt][nt][rg];
        s += v; s2 += v * v;
      }
    s  += __shfl_xor(s, 16, 64);  s  += __shfl_xor(s, 32, 64);
    s2 += __shfl_xor(s2, 16, 64); s2 += __shfl_xor(s2, 32, 64);
    if (lane < 16) {
      int c = n0 + wn2 * 32 + nt * 16 + m16;
      atomicAdd(&Ssum[c], s);
      atomicAdd(&Ssq[c], s2);
    }
  }

  // store yG[c][row] via LDS transpose (coalesced 64B runs)
  __syncthreads();
  float* Yl = (float*)Ah;                // 64 x 68 floats (fits in Ah)
#pragma unroll
  for (int mt = 0; mt < 2; ++mt)
#pragma unroll
    for (int nt = 0; nt < 2; ++nt)
#pragma unroll
      for (int rg = 0; rg < 4; ++rg)
        Yl[(wn2 * 32 + nt * 16 + m16) * 68 + wm * 32 + mt * 16 + q * 4 + rg] =
            y[mt][nt][rg];
  __syncthreads();
  {
    int c = tid >> 2, seg = (tid & 3) * 16;
#pragma unroll
    for (int j = 0; j < 16; j += 4)
      *(float4*)&yG[(n0 + c) * 2048 + row0 + seg + j] =
          *(const float4*)&Yl[c * 68 + seg + j];
  }
}

// ------------------------------------------------------------------ ab ------
// grid 352: blocks 0..255 = ab GEMM (scale/shift computed inline from atomic
// sums); 256..351 = wsplit for w1..w3.
__global__ __launch_bounds__(256) void ab_kernel(
    const float* __restrict__ yG, const float* __restrict__ Ssum,
    const float* __restrict__ Ssq,
    const float* __restrict__ g0, const float* __restrict__ be0,
    const float* __restrict__ g1, const float* __restrict__ be1,
    const float* __restrict__ mask, const float* __restrict__ w0,
    const float* __restrict__ w1, const float* __restrict__ w2,
    const float* __restrict__ w3, uint32_t* __restrict__ wpk,
    float* __restrict__ a_arr, float* __restrict__ bb_arr)
{
  int bx = blockIdx.x;
  int tid = threadIdx.x;
  if (bx >= 256) {
    int e = (bx - 256) * 256 + tid;       // 0..24575 (L, k2, n)
    int L = e >> 13;
    int r = e & 8191;
    int k2 = r >> 7, n = r & 127;
    int k = k2 * 2;
    const float* w = (L == 0) ? w1 : (L == 1) ? w2 : w3;
    uint32_t hw, lw;
    split2(w[k * 128 + n], w[(k + 1) * 128 + n], hw, lw);
    wpk[L * 8192 + n * 64 + k2] = hw;
    wpk[24576 + L * 8192 + n * 64 + k2] = lw;
    return;
  }
  __shared__ float As[32 * 36];
  __shared__ float Ws[32 * 68];
  __shared__ float scs[384], shs[384];
  // scale/shift from fused-atomics stats (BN + gamma/beta fold)
  for (int c = tid; c < 384; c += 256) {
    float Sv = Ssum[c], S2v = Ssq[c];
    float mean = Sv * (1.f / 2048.f);
    float var  = S2v * (1.f / 2048.f) - mean * mean;
    float g  = (c < 256) ? g0[c] : g1[c - 256];
    float be = (c < 256) ? be0[c] : be1[c - 256];
    float sc = g / sqrtf(var + 1e-5f);
    scs[c] = sc;
    shs[c] = be - mean * sc;
  }
  __syncthreads();

  int rt = bx & 63, ct = bx >> 6;
  int row0 = rt * 32, n0 = ct * 64;
  int r4 = (tid >> 5) * 4;
  int n2 = (tid & 31) * 2;
  int scc = tid >> 3, srr4 = (tid & 7) * 4;
  int wnn8 = (tid & 7) * 8;
  const float* wbase = (n0 < 128) ? (w0 + n0) : (w0 + CCH * 128 + (n0 - 128));
  float4 mv = *(const float4*)(mask + row0 + srr4);

  float acc[4][2] = {{0.f, 0.f}};
#pragma unroll 1
  for (int c0 = 0; c0 < 384; c0 += 32) {
    int c = c0 + scc;
    float4 yv = *(const float4*)(yG + c * 2048 + row0 + srr4);
    float sc = scs[c], sh = shs[c];
    float4 wv0 = *(const float4*)(wbase + c * 128 + wnn8);
    float4 wv1 = *(const float4*)(wbase + c * 128 + wnn8 + 4);
    __syncthreads();
    float4 hv;
    hv.x = leaky(fmaf(yv.x, sc, sh)) * mv.x;
    hv.y = leaky(fmaf(yv.y, sc, sh)) * mv.y;
    hv.z = leaky(fmaf(yv.z, sc, sh)) * mv.z;
    hv.w = leaky(fmaf(yv.w, sc, sh)) * mv.w;
    *(float4*)&As[scc * 36 + srr4] = hv;
    *(float4*)&Ws[scc * 68 + wnn8] = wv0;
    *(float4*)&Ws[scc * 68 + wnn8 + 4] = wv1;
    __syncthreads();
#pragma unroll
    for (int cc = 0; cc < 32; ++cc) {
      float4 a = *(const float4*)&As[cc * 36 + r4];
      float2 w = *(const float2*)&Ws[cc * 68 + n2];
      acc[0][0] = fmaf(a.x, w.x, acc[0][0]); acc[0][1] = fmaf(a.x, w.y, acc[0][1]);
      acc[1][0] = fmaf(a.y, w.x, acc[1][0]); acc[1][1] = fmaf(a.y, w.y, acc[1][1]);
      acc[2][0] = fmaf(a.z, w.x, acc[2][0]); acc[2][1] = fmaf(a.z, w.y, acc[2][1]);
      acc[3][0] = fmaf(a.w, w.x, acc[3][0]); acc[3][1] = fmaf(a.w, w.y, acc[3][1]);
    }
  }
  float* dst; int nd;
  if (n0 < 128) { dst = a_arr; nd = n0; } else { dst = bb_arr; nd = n0 - 128; }
#pragma unroll
  for (int ri = 0; ri < 4; ++ri)
    *(float2*)&dst[(row0 + r4 + ri) * 128 + nd + n2] = make_float2(acc[ri][0], acc[ri][1]);
}

// ---------------------------------------------------------------- pair ------
// R16: grid (64,32), one (i,b) per block, 64 j-rows, K=128. 8 waves 1m x 8n.
// Weight frags ks-double-buffered from wpk (L2) with cross-layer hoist:
// every weight load hidden under staging, MFMAs, or the rewrite phase.
__global__ __launch_bounds__(512, 3) void pair_kernel(
    const float* __restrict__ a_arr, const float* __restrict__ bb_arr,
    const float* __restrict__ b0, const uint32_t* __restrict__ wpk,
    const float* __restrict__ b1, const float* __restrict__ b2,
    const float* __restrict__ b3,
    const float* __restrict__ w4, const float* __restrict__ b4,
    const float* __restrict__ w5, const float* __restrict__ b5,
    const float* __restrict__ mask, float* __restrict__ out)
{
  __shared__ uint32_t Ahs[64 * 68];
  __shared__ uint32_t Als[64 * 68];
  int i = blockIdx.x, b = blockIdx.y;
  int tid = threadIdx.x;
  int browp = i * BB + b;                 // output row (i,b) in (L*B)

  int wid = __builtin_amdgcn_readfirstlane(tid >> 6);
  int lane = tid & 63;
  int m16 = lane & 15, q = lane >> 4;
  int wn16 = wid * 16;
  int wrow = wn16 + m16;                  // this lane's N column 0..127

  // issue (L0, ks0) weight loads first: latency hides under A staging
  F8 Wh, Wl, Whn, Wln;
  {
    const uint32_t* W0h = wpk + wrow * 64 + q * 4;
    const uint32_t* W0l = wpk + 24576 + wrow * 64 + q * 4;
    Wh.q = *(const uint4*)W0h;
    Wl.q = *(const uint4*)W0l;
  }

  // ---- stage A = leaky(a_i + bb_j + b0), split to f16 hi/lo planes
  {
    int k8 = (tid & 15) * 8;              // same for both its (512 % 16 == 0)
    const float* ap = a_arr + browp * 128 + k8;
    const float* zp = b0 + k8;
    float az[8];
#pragma unroll
    for (int t = 0; t < 8; t += 4) {
      float4 av = *(const float4*)(ap + t);
      float4 zv = *(const float4*)(zp + t);
      az[t + 0] = av.x + zv.x; az[t + 1] = av.y + zv.y;
      az[t + 2] = av.z + zv.z; az[t + 3] = av.w + zv.w;
    }
#pragma unroll
    for (int it = 0; it < 2; ++it) {
      int r = (it * 512 + tid) >> 4;      // j row 0..63
      const float* bbp = bb_arr + (r * BB + b) * 128 + k8;
      float d[8];
#pragma unroll
      for (int t = 0; t < 8; t += 4) {
        float4 bv = *(const float4*)(bbp + t);
        d[t + 0] = leaky(az[t + 0] + bv.x);
        d[t + 1] = leaky(az[t + 1] + bv.y);
        d[t + 2] = leaky(az[t + 2] + bv.z);
        d[t + 3] = leaky(az[t + 3] + bv.w);
      }
      uint4 hq, lq;
      split2(d[0], d[1], hq.x, lq.x);
      split2(d[2], d[3], hq.y, lq.y);
      split2(d[4], d[5], hq.z, lq.z);
      split2(d[6], d[7], hq.w, lq.w);
      *(uint4*)&Ahs[r * 68 + k8 / 2] = hq;
      *(uint4*)&Als[r * 68 + k8 / 2] = lq;
    }
  }
  __syncthreads();

  f32x4 hi[4], cr[4];

#pragma unroll 1
  for (int L = 0; L < 3; ++L) {
    const uint32_t* WhL = wpk + L * 8192;
    const uint32_t* WlL = wpk + 24576 + L * 8192;
    const float* Bv = (L == 0) ? b1 : (L == 1) ? b2 : b3;
#pragma unroll
    for (int mt = 0; mt < 4; ++mt) {
      hi[mt] = (f32x4){0.f, 0.f, 0.f, 0.f};
      cr[mt] = (f32x4){0.f, 0.f, 0.f, 0.f};
    }

#pragma unroll
    for (int ks = 0; ks < 4; ++ks) {
      int koff = ks * 16 + q * 4;
      // prefetch next weight frag: ks+1 within layer, or (L+1, ks0)
      // issued before the MFMAs -> latency hides under them (or under
      // the rewrite phase for the cross-layer hoist).
      if (ks < 3) {
        Whn.q = *(const uint4*)(WhL + wrow * 64 + koff + 16);
        Wln.q = *(const uint4*)(WlL + wrow * 64 + koff + 16);
      } else if (L < 2) {
        Whn.q = *(const uint4*)(WhL + 8192 + wrow * 64 + q * 4);
        Wln.q = *(const uint4*)(WlL + 8192 + wrow * 64 + q * 4);
      }
#pragma unroll
      for (int mt = 0; mt < 4; ++mt) {
        int arow = mt * 16 + m16;
        F8 Ah, Al;
        Ah.q = *(const uint4*)&Ahs[arow * 68 + koff];
        Al.q = *(const uint4*)&Als[arow * 68 + koff];
        hi[mt] = __builtin_amdgcn_mfma_f32_16x16x32_f16(
            Ah.h, Wh.h, hi[mt], 0, 0, 0);
        cr[mt] = __builtin_amdgcn_mfma_f32_16x16x32_f16(
            Ah.h, Wl.h, cr[mt], 0, 0, 0);
        cr[mt] = __builtin_amdgcn_mfma_f32_16x16x32_f16(
            Al.h, Wh.h, cr[mt], 0, 0, 0);
      }
      Wh = Whn; Wl = Wln;
    }

    float bias = Bv[wrow];

    if (L < 2) {
      __syncthreads();
      int par = lane & 1;
      int colw = (wn16 + (m16 & ~1)) >> 1;
#pragma unroll
      for (int mt = 0; mt < 4; ++mt) {
#pragma unroll
        for (int rg = 0; rg < 4; ++rg) {
          float d = leaky(hi[mt][rg] + cr[mt][rg] * (1.0f / 2048.0f) + bias);
          float dn = __shfl_xor(d, 1, 64);
          float de = par ? dn : d;
          float do_ = par ? d : dn;
          uint32_t hw, lw;
          split2(de, do_, hw, lw);
          int row = mt * 16 + q * 4 + rg;
          if (par) Als[row * 68 + colw] = lw;
          else     Ahs[row * 68 + colw] = hw;
        }
      }
      __syncthreads();
    } else {
      // mean over j (this block holds all 64 j for its (i,b));
      // each lane sums its 16 rows, q-fold completes the 64-row sum per col
      float s = 0.f;
#pragma unroll
      for (int mt = 0; mt < 4; ++mt)
#pragma unroll
        for (int rg = 0; rg < 4; ++rg)
          s += leaky(hi[mt][rg] + cr[mt][rg] * (1.0f / 2048.0f) + bias);
      s += __shfl_xor(s, 16, 64);
      s += __shfl_xor(s, 32, 64);
      float mfac = (1.0f / 64.0f) * mask[browp];
      __syncthreads();
      float* scratch = (float*)Ahs;
      float* Pm = scratch;            // p vector (128)
      float* Tp = scratch + 128;      // 4 partial chunks x 128
      float* T4 = scratch + 640;      // leaky(p@w4+b4) (128)
      if (lane < 16) Pm[wrow] = s * mfac;
      __syncthreads();
      {
        int k = tid & 127, chh = tid >> 7;     // 4 chunks of 32 c
        const float* w4c = w4 + (chh * 32) * 128 + k;
        const float* pc = Pm + chh * 32;
        float t = 0.f;
#pragma unroll 8
        for (int c0 = 0; c0 < 32; c0 += 4) {
          float4 pv = *(const float4*)&pc[c0];
          t = fmaf(pv.x, w4c[(c0 + 0) * 128], t);
          t = fmaf(pv.y, w4c[(c0 + 1) * 128], t);
          t = fmaf(pv.z, w4c[(c0 + 2) * 128], t);
          t = fmaf(pv.w, w4c[(c0 + 3) * 128], t);
        }
        Tp[chh * 128 + k] = t;
      }
      __syncthreads();
      if (tid < 128)
        T4[tid] = leaky(Tp[tid] + Tp[128 + tid] + Tp[256 + tid] +
                        Tp[384 + tid] + b4[tid]);
      __syncthreads();
      {
        float o = b5[tid];
#pragma unroll 4
        for (int c0 = 0; c0 < 128; c0 += 4) {
          float4 tv = *(const float4*)&T4[c0];
          o = fmaf(tv.x, w5[(c0 + 0) * 512 + tid], o);
          o = fmaf(tv.y, w5[(c0 + 1) * 512 + tid], o);
          o = fmaf(tv.z, w5[(c0 + 2) * 512 + tid], o);
          o = fmaf(tv.w, w5[(c0 + 3) * 512 + tid], o);
        }
        out[browp * 512 + tid] = leaky(o) * mask[browp];
      }
    }
  }
}

// -------------------------------------------------------------- launch ------
extern "C" void kernel_launch(void* const* d_in, const int* in_sizes, int n_in,
                              void* d_out, int out_size, void* d_ws, size_t ws_size,
                              hipStream_t stream) {
  const float* x    = (const float*)d_in[0];
  const float* mask = (const float*)d_in[1];
  const float* cw0  = (const float*)d_in[2];
  // d_in[3] conv_b0: cancels in BN
  const float* g0   = (const float*)d_in[4];
  const float* be0  = (const float*)d_in[5];
  const float* cw1  = (const float*)d_in[6];
  // d_in[7] conv_b1: cancels in BN
  const float* g1   = (const float*)d_in[8];
  const float* be1  = (const float*)d_in[9];
  const float* w0   = (const float*)d_in[10];
  const float* b0   = (const float*)d_in[11];
  const float* w1   = (const float*)d_in[12];
  const float* b1   = (const float*)d_in[13];
  const float* w2   = (const float*)d_in[14];
  const float* b2   = (const float*)d_in[15];
  const float* w3   = (const float*)d_in[16];
  const float* b3   = (const float*)d_in[17];
  const float* w4   = (const float*)d_in[18];
  const float* b4   = (const float*)d_in[19];
  const float* w5   = (const float*)d_in[20];
  const float* b5   = (const float*)d_in[21];

  float* ws     = (float*)d_ws;
  float* Ssum   = ws;                         // 384
  float* Ssq    = ws + 384;                   // 384
  float* yG     = ws + 768;                   // 384*2048 = 786432
  uint32_t* wpk = (uint32_t*)(ws + 787200);   // 49152
  float* a_arr  = ws + 836352;                // 2048*128
  float* bb_arr = ws + 1098496;               // 2048*128
  float* outp   = (float*)d_out;

  hipMemsetAsync(Ssum, 0, 768 * sizeof(float), stream);
  conv_kernel<<<192, 256, 0, stream>>>(x, mask, cw0, cw1, yG, Ssum, Ssq);
  ab_kernel<<<352, 256, 0, stream>>>(yG, Ssum, Ssq, g0, be0, g1, be1,
                                     mask, w0, w1, w2, w3, wpk, a_arr, bb_arr);
  dim3 g5(64, 32);
  pair_kernel<<<g5, 512, 0, stream>>>(a_arr, bb_arr, b0, wpk, b1, b2, b3,
                                      w4, b4, w5, b5, mask, outp);
}